// Round 14
// baseline (302.842 us; speedup 1.0000x reference)
//
#include <hip/hip_runtime.h>
#include <hip/hip_bf16.h>

typedef __attribute__((ext_vector_type(8))) short bf16x8;
typedef __attribute__((ext_vector_type(4))) float f32x4;
typedef unsigned short u16;

#define NTOK 2048
#define DDIM 1024
#define HDIM 4096
#define KEXP 8

#define BM 320   // covers any realistic expert count in ONE tile (counts ~256±15)
#define BK 64
#define NDESC 16

__device__ __forceinline__ u16 f2bf(float f) {
  __hip_bfloat16 b = __float2bfloat16(f);   // RNE; compiler fuses pairs to v_cvt_pk_bf16_f32
  union { __hip_bfloat16 b; u16 u; } c; c.b = b; return c.u;
}
__device__ __forceinline__ unsigned pk2(float a, float b) {
  return (unsigned)f2bf(a) | ((unsigned)f2bf(b) << 16);
}

// fenced raw barrier: own DS ops drained, no vmcnt drain, no code motion across
#define BAR() do { \
  asm volatile("s_waitcnt lgkmcnt(0)" ::: "memory"); \
  __builtin_amdgcn_sched_barrier(0); \
  __builtin_amdgcn_s_barrier(); \
  __builtin_amdgcn_sched_barrier(0); \
} while (0)

// ---------------- routing: counting sort + tile worklist ----------------
__global__ void route_kernel(const float* __restrict__ cw, int* __restrict__ offs,
                             int* __restrict__ perm, float* __restrict__ wsel,
                             int* __restrict__ desc) {
  __shared__ int cnt[KEXP];
  __shared__ int base[KEXP];
  const int t = threadIdx.x;  // 256 threads, 8 tokens each
  if (t < KEXP) cnt[t] = 0;
  __syncthreads();
  int eid[8]; float wv[8];
  #pragma unroll
  for (int i = 0; i < 8; i++) {
    const int tok = t * 8 + i;
    const float* p = cw + tok * KEXP;
    int best = 0; float bw = p[0];
    #pragma unroll
    for (int k = 1; k < KEXP; k++) { float v = p[k]; if (v > bw) { bw = v; best = k; } }
    eid[i] = best; wv[i] = bw;
    atomicAdd(&cnt[best], 1);
  }
  __syncthreads();
  if (t == 0) {
    int s = 0, nd = 0;
    for (int k = 0; k < KEXP; k++) {
      const int ck = cnt[k];
      base[k] = s; offs[k] = s;
      for (int m0 = 0; m0 < ck && nd < NDESC; m0 += BM)
        desc[nd++] = (k << 12) | (s + m0);   // pack expert(3b) | slot0(12b)
      s += ck;
    }
    offs[KEXP] = s;
    for (; nd < NDESC; nd++) desc[nd] = -1;
  }
  __syncthreads();
  #pragma unroll
  for (int i = 0; i < 8; i++) {
    const int tok = t * 8 + i;
    const int pos = atomicAdd(&base[eid[i]], 1);
    perm[pos] = tok;
    wsel[pos] = wv[i];
  }
}

// ---------------- gather x rows into expert-sorted bf16 ----------------
__global__ void gather_x(const float* __restrict__ x, const int* __restrict__ perm,
                         u16* __restrict__ Xb) {
  const int slot = blockIdx.x;
  const int tok = perm[slot];
  const int t = threadIdx.x;  // 256
  float4 v = ((const float4*)(x + (size_t)tok * DDIM))[t];
  ushort4 o; o.x = f2bf(v.x); o.y = f2bf(v.y); o.z = f2bf(v.z); o.w = f2bf(v.w);
  ((ushort4*)(Xb + (size_t)slot * DDIM))[t] = o;
}

// ---------------- pass 1: H = silu(X@wg) * (X@wu) ----------------
// 512 thr = 8 waves (4m x 2n), BM=320, BN=32, BK=64, wave tile 80x16 per matrix.
// A-DIRECT: MFMA A-fragments loaded straight from Xb (bf16, L2-resident) as
// per-lane b128 (wave = 16 rows x 64B = 16 full cache lines). NO A LDS at all.
// B: reg-staged f32->bf16, XOR-swizzled LDS dbuf, early issue, no vmcnt(0).
// LDS = 16 KB -> 2 blocks/CU resident: cross-block overlap hides barriers.
__global__ __launch_bounds__(512, 4) void gemm_swiglu(
    const u16* __restrict__ Xb,
    const float* __restrict__ wg, const float* __restrict__ wu,
    const int* __restrict__ offs, const int* __restrict__ desc,
    u16* __restrict__ Hb) {
  __shared__ u16 Bs[2][2][32 * 64];    // 16 KB  [buf][mat][n*64 ^swz]

  const int d = desc[blockIdx.y];
  if (d < 0) return;
  const int e = d >> 12;
  const int slot0 = d & 0xFFF;
  const int Msub = offs[e + 1] - slot0;
  const int n0 = blockIdx.x * 32;

  const int t = threadIdx.x;
  const int lane = t & 63;
  const int W = t >> 6;      // 0..7
  const int wm = W >> 1;     // 4 m-strips of 80 rows
  const int wn = W & 1;      // 2 n-strips of 16 cols
  const int l15 = lane & 15;
  const int lhi = lane >> 4;

  // A-direct per-lane fragment bases (one per fm, row-clamped)
  const u16* aP[5];
  #pragma unroll
  for (int fm = 0; fm < 5; fm++)
    aP[fm] = Xb + (size_t)min(slot0 + wm * 80 + fm * 16 + l15, NTOK - 1) * DDIM + lhi * 8;

  // B staging: t<256 -> G(wg), else U(wu); thread -> (n = tb&31, chunk c = tb>>5)
  const int tb = t & 255;
  const int matsel = t >> 8;
  const float* b_base = (matsel ? wu : wg) + (size_t)e * DDIM * HDIM;
  const int b_n = tb & 31;
  const int b_c = tb >> 5;
  const float* b_src = b_base + (size_t)(b_c * 8) * HDIM + n0 + b_n;
  const int b_off = b_n * 64 + ((b_c ^ (b_n & 7)) << 3);

  float bR[8];
  f32x4 accg[5] = {};
  f32x4 accu[5] = {};

  #define LOADB(tile) { const float* p_ = b_src + (size_t)(tile) * BK * HDIM; \
    _Pragma("unroll") for (int j = 0; j < 8; j++) bR[j] = p_[(size_t)j * HDIM]; }
  #define WRITEB(buf) { uint4 w_; \
    w_.x = pk2(bR[0], bR[1]); w_.y = pk2(bR[2], bR[3]); \
    w_.z = pk2(bR[4], bR[5]); w_.w = pk2(bR[6], bR[7]); \
    *(uint4*)(&Bs[buf][matsel][b_off]) = w_; }
  #define COMPUTE(buf, itv) { _Pragma("unroll") for (int ks = 0; ks < 2; ks++) { \
      const int cx_ = (((ks << 2) + lhi) ^ (l15 & 7)) << 3; \
      bf16x8 bg_ = *(const bf16x8*)(&Bs[buf][0][(wn * 16 + l15) * 64] + cx_); \
      bf16x8 bu_ = *(const bf16x8*)(&Bs[buf][1][(wn * 16 + l15) * 64] + cx_); \
      const int ao_ = (itv) * 64 + ks * 32; \
      _Pragma("unroll") for (int fm = 0; fm < 5; fm++) { \
        bf16x8 af_ = *(const bf16x8*)(aP[fm] + ao_); \
        accg[fm] = __builtin_amdgcn_mfma_f32_16x16x32_bf16(af_, bg_, accg[fm], 0, 0, 0); \
        accu[fm] = __builtin_amdgcn_mfma_f32_16x16x32_bf16(af_, bu_, accu[fm], 0, 0, 0); } } }

  // prologue: B(0) -> buf0; leave bR = tile1
  LOADB(0);
  WRITEB(0);
  LOADB(1);
  BAR();

  #pragma unroll 1
  for (int it = 0; it < 16; it += 2) {
    // even: write tile it+1 -> buf1; issue B(it+2); compute tile it (buf0)
    WRITEB(1);
    if (it + 2 < 16) LOADB(it + 2);
    COMPUTE(0, it);
    BAR();
    // odd: write tile it+2 -> buf0; issue B(it+3); compute tile it+1 (buf1)
    if (it + 2 < 16) { WRITEB(0); if (it + 3 < 16) LOADB(it + 3); }
    COMPUTE(1, it + 1);
    BAR();
  }
  #undef LOADB
  #undef WRITEB
  #undef COMPUTE

  // epilogue: silu(g)*u -> bf16 Hb  (C/D map: col=lane&15, row=(lane>>4)*4+i)
  #pragma unroll
  for (int fm = 0; fm < 5; fm++) {
    #pragma unroll
    for (int i = 0; i < 4; i++) {
      const int row = wm * 80 + fm * 16 + lhi * 4 + i;
      if (row < Msub) {
        const float g = accg[fm][i];
        const float u = accu[fm][i];
        const float h = (g / (1.0f + __expf(-g))) * u;
        Hb[(size_t)(slot0 + row) * HDIM + n0 + wn * 16 + l15] = f2bf(h);
      }
    }
  }
}

// ---------------- pass 2: Y = (H @ wd) * wsel, split-K=4, scatter-add ----------------
// 512 thr = 8 waves (4m x 2n), BM=320, BN=64, wave tile 80x32. A-direct from Hb.
__global__ __launch_bounds__(512, 4) void gemm_down(
    const u16* __restrict__ Hb, const float* __restrict__ wd,
    const int* __restrict__ offs, const int* __restrict__ desc,
    const int* __restrict__ perm, const float* __restrict__ wsel,
    float* __restrict__ y) {
  __shared__ u16 Bs[2][64 * 64];       // 16 KB

  const int d = desc[blockIdx.y];
  if (d < 0) return;
  const int e = d >> 12;
  const int slot0 = d & 0xFFF;
  const int Msub = offs[e + 1] - slot0;
  const int n0 = blockIdx.x * 64;
  const int kbase = blockIdx.z * (HDIM / 4);

  const float* Wd = wd + (size_t)e * HDIM * DDIM;

  const int t = threadIdx.x;
  const int lane = t & 63;
  const int W = t >> 6;
  const int wm = W >> 1;   // 4 m-strips of 80
  const int wn = W & 1;    // 2 n-strips of 32
  const int l15 = lane & 15;
  const int lhi = lane >> 4;

  const u16* aP[5];
  #pragma unroll
  for (int fm = 0; fm < 5; fm++)
    aP[fm] = Hb + (size_t)min(slot0 + wm * 80 + fm * 16 + l15, NTOK - 1) * HDIM + kbase + lhi * 8;

  // B staging: thread -> (n = t&63, chunk c = t>>6)
  const int b_n = t & 63;
  const int b_c = t >> 6;
  const float* b_src = Wd + (size_t)(kbase + b_c * 8) * DDIM + n0 + b_n;
  const int b_off = b_n * 64 + ((b_c ^ (b_n & 7)) << 3);

  float bR[8];
  f32x4 acc[5][2] = {};

  #define LOADB(tile) { const float* p_ = b_src + (size_t)(tile) * BK * DDIM; \
    _Pragma("unroll") for (int j = 0; j < 8; j++) bR[j] = p_[(size_t)j * DDIM]; }
  #define WRITEB(buf) { uint4 w_; \
    w_.x = pk2(bR[0], bR[1]); w_.y = pk2(bR[2], bR[3]); \
    w_.z = pk2(bR[4], bR[5]); w_.w = pk2(bR[6], bR[7]); \
    *(uint4*)(&Bs[buf][b_off]) = w_; }
  #define COMPUTE(buf, itv) { _Pragma("unroll") for (int ks = 0; ks < 2; ks++) { \
      const int cx_ = (((ks << 2) + lhi) ^ (l15 & 7)) << 3; \
      bf16x8 bf0_ = *(const bf16x8*)(&Bs[buf][(wn * 32 + l15) * 64] + cx_); \
      bf16x8 bf1_ = *(const bf16x8*)(&Bs[buf][(wn * 32 + 16 + l15) * 64] + cx_); \
      const int ao_ = (itv) * 64 + ks * 32; \
      _Pragma("unroll") for (int fm = 0; fm < 5; fm++) { \
        bf16x8 af_ = *(const bf16x8*)(aP[fm] + ao_); \
        acc[fm][0] = __builtin_amdgcn_mfma_f32_16x16x32_bf16(af_, bf0_, acc[fm][0], 0, 0, 0); \
        acc[fm][1] = __builtin_amdgcn_mfma_f32_16x16x32_bf16(af_, bf1_, acc[fm][1], 0, 0, 0); } } }

  LOADB(0);
  WRITEB(0);
  LOADB(1);
  BAR();

  #pragma unroll 1
  for (int it = 0; it < 16; it += 2) {
    WRITEB(1);
    if (it + 2 < 16) LOADB(it + 2);
    COMPUTE(0, it);
    BAR();
    if (it + 2 < 16) { WRITEB(0); if (it + 3 < 16) LOADB(it + 3); }
    COMPUTE(1, it + 1);
    BAR();
  }
  #undef LOADB
  #undef WRITEB
  #undef COMPUTE

  // epilogue: scale by routing weight, scatter-add (4 K-quarters, commutative)
  #pragma unroll
  for (int fm = 0; fm < 5; fm++) {
    #pragma unroll
    for (int i = 0; i < 4; i++) {
      const int row = wm * 80 + fm * 16 + lhi * 4 + i;
      if (row < Msub) {
        const int slot = slot0 + row;
        const int tok = perm[slot];
        const float w = wsel[slot];
        const size_t base = (size_t)tok * DDIM + n0 + wn * 32;
        atomicAdd(y + base + l15, acc[fm][0][i] * w);
        atomicAdd(y + base + 16 + l15, acc[fm][1][i] * w);
      }
    }
  }
}

extern "C" void kernel_launch(void* const* d_in, const int* in_sizes, int n_in,
                              void* d_out, int out_size, void* d_ws, size_t ws_size,
                              hipStream_t stream) {
  const float* x  = (const float*)d_in[0];
  const float* cw = (const float*)d_in[1];
  const float* wg = (const float*)d_in[2];
  const float* wu = (const float*)d_in[3];
  const float* wd = (const float*)d_in[4];
  float* y = (float*)d_out;

  char* ws = (char*)d_ws;
  int* offs   = (int*)ws;                          // 16 ints
  int* desc   = (int*)(ws + 64);                   // 16 ints
  int* perm   = (int*)(ws + 128);                  // 2048 ints
  float* wsel = (float*)(ws + 128 + NTOK * 4);     // 2048 floats
  u16* Xb = (u16*)(ws + 32768);                                    // 4 MB
  u16* Hb = (u16*)(ws + 32768 + (size_t)NTOK * DDIM * 2);          // 16 MB

  hipMemsetAsync(d_out, 0, (size_t)NTOK * DDIM * sizeof(float), stream);
  route_kernel<<<1, 256, 0, stream>>>(cw, offs, perm, wsel, desc);
  gather_x<<<NTOK, 256, 0, stream>>>(x, perm, Xb);
  gemm_swiglu<<<dim3(HDIM / 32, NDESC), 512, 0, stream>>>(Xb, wg, wu, offs, desc, Hb);
  gemm_down<<<dim3(DDIM / 64, NDESC, 4), 512, 0, stream>>>(Hb, wd, offs, desc, perm, wsel, y);
}

// Round 15
// 220.384 us; speedup vs baseline: 1.3742x; 1.3742x over previous
//
#include <hip/hip_runtime.h>
#include <hip/hip_bf16.h>

typedef __attribute__((ext_vector_type(8))) short bf16x8;
typedef __attribute__((ext_vector_type(4))) float f32x4;
typedef unsigned short u16;

#define NTOK 2048
#define DDIM 1024
#define HDIM 4096
#define KEXP 8

#define BM 320   // covers any realistic expert count in ONE tile (counts ~256±15)
#define BK 64
#define NDESC 16

__device__ __forceinline__ u16 f2bf(float f) {
  __hip_bfloat16 b = __float2bfloat16(f);   // RNE; pairs fuse to v_cvt_pk_bf16_f32
  union { __hip_bfloat16 b; u16 u; } c; c.b = b; return c.u;
}
__device__ __forceinline__ unsigned pk2(float a, float b) {
  return (unsigned)f2bf(a) | ((unsigned)f2bf(b) << 16);
}

// fenced raw barrier: own DS ops drained, no vmcnt drain, no code motion across
#define BAR2() do { \
  asm volatile("s_waitcnt lgkmcnt(0)" ::: "memory"); \
  __builtin_amdgcn_sched_barrier(0); \
  __builtin_amdgcn_s_barrier(); \
  __builtin_amdgcn_sched_barrier(0); \
} while (0)

// ---------------- routing: counting sort + tile worklist ----------------
__global__ void route_kernel(const float* __restrict__ cw, int* __restrict__ offs,
                             int* __restrict__ perm, float* __restrict__ wsel,
                             int* __restrict__ desc) {
  __shared__ int cnt[KEXP];
  __shared__ int base[KEXP];
  const int t = threadIdx.x;  // 256 threads, 8 tokens each
  if (t < KEXP) cnt[t] = 0;
  __syncthreads();
  int eid[8]; float wv[8];
  #pragma unroll
  for (int i = 0; i < 8; i++) {
    const int tok = t * 8 + i;
    const float* p = cw + tok * KEXP;
    int best = 0; float bw = p[0];
    #pragma unroll
    for (int k = 1; k < KEXP; k++) { float v = p[k]; if (v > bw) { bw = v; best = k; } }
    eid[i] = best; wv[i] = bw;
    atomicAdd(&cnt[best], 1);
  }
  __syncthreads();
  if (t == 0) {
    int s = 0, nd = 0;
    for (int k = 0; k < KEXP; k++) {
      const int ck = cnt[k];
      base[k] = s; offs[k] = s;
      for (int m0 = 0; m0 < ck && nd < NDESC; m0 += BM)
        desc[nd++] = (k << 12) | (s + m0);   // pack expert(3b) | slot0(12b)
      s += ck;
    }
    offs[KEXP] = s;
    for (; nd < NDESC; nd++) desc[nd] = -1;
  }
  __syncthreads();
  #pragma unroll
  for (int i = 0; i < 8; i++) {
    const int tok = t * 8 + i;
    const int pos = atomicAdd(&base[eid[i]], 1);
    perm[pos] = tok;
    wsel[pos] = wv[i];
  }
}

// ---------------- gather x rows into expert-sorted bf16 ----------------
__global__ void gather_x(const float* __restrict__ x, const int* __restrict__ perm,
                         u16* __restrict__ Xb) {
  const int slot = blockIdx.x;
  const int tok = perm[slot];
  const int t = threadIdx.x;  // 256
  float4 v = ((const float4*)(x + (size_t)tok * DDIM))[t];
  ushort4 o; o.x = f2bf(v.x); o.y = f2bf(v.y); o.z = f2bf(v.z); o.w = f2bf(v.w);
  ((ushort4*)(Xb + (size_t)slot * DDIM))[t] = o;
}

// ---------------- pass 1: H = silu(X@wg) * (X@wu) ----------------
// 512 thr = 8 waves (4m x 2n), BM=320, BN=32, BK=64; each wave: 80x16 tile,
// BOTH matrices (acc=40). LDS 56 KB -> 2 blocks/CU: cross-block TLP covers
// barrier/latency stalls (the 1-block/CU schedules all plateaued at ~105us).
// A: single-buffer sync stage (R6-proven). B: swizzled dbuf, reg prefetch,
// raw fenced B2 (no vmcnt drain). Swizzle: chunk c -> c^(row&7), 0 conflicts.
__global__ __launch_bounds__(512, 4) void gemm_swiglu(
    const u16* __restrict__ Xb,
    const float* __restrict__ wg, const float* __restrict__ wu,
    const int* __restrict__ offs, const int* __restrict__ desc,
    u16* __restrict__ Hb) {
  __shared__ u16 As[BM * 64];          // 40 KB (single buffer)
  __shared__ u16 Bs[2][2][32 * 64];    // 16 KB  [buf][mat][n*64 ^swz]

  const int d = desc[blockIdx.y];
  if (d < 0) return;
  const int e = d >> 12;
  const int slot0 = d & 0xFFF;
  const int Msub = offs[e + 1] - slot0;
  const int n0 = blockIdx.x * 32;

  const int t = threadIdx.x;
  const int lane = t & 63;
  const int W = t >> 6;      // 0..7
  const int wm = W >> 1;     // 4 m-strips of 80 rows
  const int wn = W & 1;      // 2 n-strips of 16 cols
  const int l15 = lane & 15;
  const int lhi = lane >> 4;

  // A staging: 640 tasks (row, 32-elem half); thread t -> task t; t<128 also task 512+t
  const int a_row1 = t >> 1;
  const int a_h1 = t & 1;
  const u16* a_src1 = Xb + (size_t)min(slot0 + a_row1, NTOK - 1) * DDIM + a_h1 * 32;
  const int a_row2 = 256 + (t >> 1);
  const u16* a_src2 = Xb + (size_t)min(slot0 + a_row2, NTOK - 1) * DDIM + a_h1 * 32;
  const bool do_a2 = t < 128;

  // B staging: t<256 -> G(wg), else U(wu); tb -> (n = tb&31, chunk c = tb>>5)
  const int tb = t & 255;
  const int matsel = t >> 8;
  const float* b_base = (matsel ? wu : wg) + (size_t)e * DDIM * HDIM;
  const int b_n = tb & 31;
  const int b_c = tb >> 5;
  const float* b_src = b_base + (size_t)(b_c * 8) * HDIM + n0 + b_n;
  const int b_off = b_n * 64 + ((b_c ^ (b_n & 7)) << 3);

  float bR[8];
  f32x4 accg[5] = {};
  f32x4 accu[5] = {};

  #define ASTAGE(tile) { \
    const uint4* p1_ = (const uint4*)(a_src1 + (tile) * BK); \
    uint4 v0_ = p1_[0], v1_ = p1_[1], v2_ = p1_[2], v3_ = p1_[3]; \
    uint4 w0_, w1_, w2_, w3_; \
    if (do_a2) { const uint4* p2_ = (const uint4*)(a_src2 + (tile) * BK); \
      w0_ = p2_[0]; w1_ = p2_[1]; w2_ = p2_[2]; w3_ = p2_[3]; } \
    u16* b1_ = &As[a_row1 * 64]; \
    const int sz1_ = a_row1 & 7; \
    *(uint4*)(b1_ + (((a_h1 * 4 + 0) ^ sz1_) << 3)) = v0_; \
    *(uint4*)(b1_ + (((a_h1 * 4 + 1) ^ sz1_) << 3)) = v1_; \
    *(uint4*)(b1_ + (((a_h1 * 4 + 2) ^ sz1_) << 3)) = v2_; \
    *(uint4*)(b1_ + (((a_h1 * 4 + 3) ^ sz1_) << 3)) = v3_; \
    if (do_a2) { u16* b2_ = &As[a_row2 * 64]; \
      const int sz2_ = a_row2 & 7; \
      *(uint4*)(b2_ + (((a_h1 * 4 + 0) ^ sz2_) << 3)) = w0_; \
      *(uint4*)(b2_ + (((a_h1 * 4 + 1) ^ sz2_) << 3)) = w1_; \
      *(uint4*)(b2_ + (((a_h1 * 4 + 2) ^ sz2_) << 3)) = w2_; \
      *(uint4*)(b2_ + (((a_h1 * 4 + 3) ^ sz2_) << 3)) = w3_; } \
  }
  #define LOADB(tile) { const float* p_ = b_src + (size_t)(tile) * BK * HDIM; \
    _Pragma("unroll") for (int j = 0; j < 8; j++) bR[j] = p_[(size_t)j * HDIM]; }
  #define WRITEB(buf) { uint4 w_; \
    w_.x = pk2(bR[0], bR[1]); w_.y = pk2(bR[2], bR[3]); \
    w_.z = pk2(bR[4], bR[5]); w_.w = pk2(bR[6], bR[7]); \
    *(uint4*)(&Bs[buf][matsel][b_off]) = w_; }
  #define COMPUTE(buf) { _Pragma("unroll") for (int ks = 0; ks < 2; ks++) { \
      const int cx_ = (((ks << 2) + lhi) ^ (l15 & 7)) << 3; \
      bf16x8 bg_ = *(const bf16x8*)(&Bs[buf][0][(wn * 16 + l15) * 64] + cx_); \
      bf16x8 bu_ = *(const bf16x8*)(&Bs[buf][1][(wn * 16 + l15) * 64] + cx_); \
      _Pragma("unroll") for (int fm = 0; fm < 5; fm++) { \
        bf16x8 af_ = *(const bf16x8*)(&As[(wm * 80 + fm * 16 + l15) * 64] + cx_); \
        accg[fm] = __builtin_amdgcn_mfma_f32_16x16x32_bf16(af_, bg_, accg[fm], 0, 0, 0); \
        accu[fm] = __builtin_amdgcn_mfma_f32_16x16x32_bf16(af_, bu_, accu[fm], 0, 0, 0); } } }

  LOADB(0);

  #pragma unroll 1
  for (int it = 0; it < 16; it += 2) {
    // phase even: stage A(it) + B(it)->buf0; issue B(it+1); compute
    if (it) __syncthreads();         // B1: As WAR (full fence; bR already arrived)
    ASTAGE(it);
    WRITEB(0);
    if (it + 1 < 16) LOADB(it + 1);
    BAR2();                          // B2: raw; B(it+1) loads stay in flight
    COMPUTE(0);
    // phase odd
    __syncthreads();
    ASTAGE(it + 1);
    WRITEB(1);
    if (it + 2 < 16) LOADB(it + 2);
    BAR2();
    COMPUTE(1);
  }
  #undef ASTAGE
  #undef LOADB
  #undef WRITEB
  #undef COMPUTE

  // epilogue: silu(g)*u -> bf16 Hb  (C/D map: col=lane&15, row=(lane>>4)*4+i)
  #pragma unroll
  for (int fm = 0; fm < 5; fm++) {
    #pragma unroll
    for (int i = 0; i < 4; i++) {
      const int row = wm * 80 + fm * 16 + lhi * 4 + i;
      if (row < Msub) {
        const float g = accg[fm][i];
        const float u = accu[fm][i];
        const float h = (g / (1.0f + __expf(-g))) * u;
        Hb[(size_t)(slot0 + row) * HDIM + n0 + wn * 16 + l15] = f2bf(h);
      }
    }
  }
}

// ---------------- pass 2: Y = (H @ wd) * wsel, split-K=4, scatter-add ----------------
// 512 thr = 8 waves (4m x 2n), BN=64, wave tile 80x32 (acc=40). LDS 56 KB -> 2/CU.
__global__ __launch_bounds__(512, 4) void gemm_down(
    const u16* __restrict__ Hb, const float* __restrict__ wd,
    const int* __restrict__ offs, const int* __restrict__ desc,
    const int* __restrict__ perm, const float* __restrict__ wsel,
    float* __restrict__ y) {
  __shared__ u16 As[BM * 64];          // 40 KB
  __shared__ u16 Bs[2][64 * 64];       // 16 KB

  const int d = desc[blockIdx.y];
  if (d < 0) return;
  const int e = d >> 12;
  const int slot0 = d & 0xFFF;
  const int Msub = offs[e + 1] - slot0;
  const int n0 = blockIdx.x * 64;
  const int kbase = blockIdx.z * (HDIM / 4);

  const float* Wd = wd + (size_t)e * HDIM * DDIM;

  const int t = threadIdx.x;
  const int lane = t & 63;
  const int W = t >> 6;
  const int wm = W >> 1;   // 4 m-strips of 80
  const int wn = W & 1;    // 2 n-strips of 32
  const int l15 = lane & 15;
  const int lhi = lane >> 4;

  const int a_row1 = t >> 1;
  const int a_h1 = t & 1;
  const u16* a_src1 = Hb + (size_t)min(slot0 + a_row1, NTOK - 1) * HDIM + kbase + a_h1 * 32;
  const int a_row2 = 256 + (t >> 1);
  const u16* a_src2 = Hb + (size_t)min(slot0 + a_row2, NTOK - 1) * HDIM + kbase + a_h1 * 32;
  const bool do_a2 = t < 128;

  // B staging: thread -> (n = t&63, chunk c = t>>6)
  const int b_n = t & 63;
  const int b_c = t >> 6;
  const float* b_src = Wd + (size_t)(kbase + b_c * 8) * DDIM + n0 + b_n;
  const int b_off = b_n * 64 + ((b_c ^ (b_n & 7)) << 3);

  float bR[8];
  f32x4 acc[5][2] = {};

  #define ASTAGE(tile) { \
    const uint4* p1_ = (const uint4*)(a_src1 + (tile) * BK); \
    uint4 v0_ = p1_[0], v1_ = p1_[1], v2_ = p1_[2], v3_ = p1_[3]; \
    uint4 w0_, w1_, w2_, w3_; \
    if (do_a2) { const uint4* p2_ = (const uint4*)(a_src2 + (tile) * BK); \
      w0_ = p2_[0]; w1_ = p2_[1]; w2_ = p2_[2]; w3_ = p2_[3]; } \
    u16* b1_ = &As[a_row1 * 64]; \
    const int sz1_ = a_row1 & 7; \
    *(uint4*)(b1_ + (((a_h1 * 4 + 0) ^ sz1_) << 3)) = v0_; \
    *(uint4*)(b1_ + (((a_h1 * 4 + 1) ^ sz1_) << 3)) = v1_; \
    *(uint4*)(b1_ + (((a_h1 * 4 + 2) ^ sz1_) << 3)) = v2_; \
    *(uint4*)(b1_ + (((a_h1 * 4 + 3) ^ sz1_) << 3)) = v3_; \
    if (do_a2) { u16* b2_ = &As[a_row2 * 64]; \
      const int sz2_ = a_row2 & 7; \
      *(uint4*)(b2_ + (((a_h1 * 4 + 0) ^ sz2_) << 3)) = w0_; \
      *(uint4*)(b2_ + (((a_h1 * 4 + 1) ^ sz2_) << 3)) = w1_; \
      *(uint4*)(b2_ + (((a_h1 * 4 + 2) ^ sz2_) << 3)) = w2_; \
      *(uint4*)(b2_ + (((a_h1 * 4 + 3) ^ sz2_) << 3)) = w3_; } \
  }
  #define LOADB(tile) { const float* p_ = b_src + (size_t)(tile) * BK * DDIM; \
    _Pragma("unroll") for (int j = 0; j < 8; j++) bR[j] = p_[(size_t)j * DDIM]; }
  #define WRITEB(buf) { uint4 w_; \
    w_.x = pk2(bR[0], bR[1]); w_.y = pk2(bR[2], bR[3]); \
    w_.z = pk2(bR[4], bR[5]); w_.w = pk2(bR[6], bR[7]); \
    *(uint4*)(&Bs[buf][b_off]) = w_; }
  #define COMPUTE(buf) { _Pragma("unroll") for (int ks = 0; ks < 2; ks++) { \
      const int cx_ = (((ks << 2) + lhi) ^ (l15 & 7)) << 3; \
      bf16x8 bf0_ = *(const bf16x8*)(&Bs[buf][(wn * 32 + l15) * 64] + cx_); \
      bf16x8 bf1_ = *(const bf16x8*)(&Bs[buf][(wn * 32 + 16 + l15) * 64] + cx_); \
      _Pragma("unroll") for (int fm = 0; fm < 5; fm++) { \
        bf16x8 af_ = *(const bf16x8*)(&As[(wm * 80 + fm * 16 + l15) * 64] + cx_); \
        acc[fm][0] = __builtin_amdgcn_mfma_f32_16x16x32_bf16(af_, bf0_, acc[fm][0], 0, 0, 0); \
        acc[fm][1] = __builtin_amdgcn_mfma_f32_16x16x32_bf16(af_, bf1_, acc[fm][1], 0, 0, 0); } } }

  LOADB(0);

  #pragma unroll 1
  for (int it = 0; it < 16; it += 2) {
    if (it) __syncthreads();
    ASTAGE(it);
    WRITEB(0);
    if (it + 1 < 16) LOADB(it + 1);
    BAR2();
    COMPUTE(0);
    __syncthreads();
    ASTAGE(it + 1);
    WRITEB(1);
    if (it + 2 < 16) LOADB(it + 2);
    BAR2();
    COMPUTE(1);
  }
  #undef ASTAGE
  #undef LOADB
  #undef WRITEB
  #undef COMPUTE

  // epilogue: scale by routing weight, scatter-add (4 K-quarters, commutative)
  #pragma unroll
  for (int fm = 0; fm < 5; fm++) {
    #pragma unroll
    for (int i = 0; i < 4; i++) {
      const int row = wm * 80 + fm * 16 + lhi * 4 + i;
      if (row < Msub) {
        const int slot = slot0 + row;
        const int tok = perm[slot];
        const float w = wsel[slot];
        const size_t base = (size_t)tok * DDIM + n0 + wn * 32;
        atomicAdd(y + base + l15, acc[fm][0][i] * w);
        atomicAdd(y + base + 16 + l15, acc[fm][1][i] * w);
      }
    }
  }
}

extern "C" void kernel_launch(void* const* d_in, const int* in_sizes, int n_in,
                              void* d_out, int out_size, void* d_ws, size_t ws_size,
                              hipStream_t stream) {
  const float* x  = (const float*)d_in[0];
  const float* cw = (const float*)d_in[1];
  const float* wg = (const float*)d_in[2];
  const float* wu = (const float*)d_in[3];
  const float* wd = (const float*)d_in[4];
  float* y = (float*)d_out;

  char* ws = (char*)d_ws;
  int* offs   = (int*)ws;                          // 16 ints
  int* desc   = (int*)(ws + 64);                   // 16 ints
  int* perm   = (int*)(ws + 128);                  // 2048 ints
  float* wsel = (float*)(ws + 128 + NTOK * 4);     // 2048 floats
  u16* Xb = (u16*)(ws + 32768);                                    // 4 MB
  u16* Hb = (u16*)(ws + 32768 + (size_t)NTOK * DDIM * 2);          // 16 MB

  hipMemsetAsync(d_out, 0, (size_t)NTOK * DDIM * sizeof(float), stream);
  route_kernel<<<1, 256, 0, stream>>>(cw, offs, perm, wsel, desc);
  gather_x<<<NTOK, 256, 0, stream>>>(x, perm, Xb);
  gemm_swiglu<<<dim3(HDIM / 32, NDESC), 512, 0, stream>>>(Xb, wg, wu, offs, desc, Hb);
  gemm_down<<<dim3(DDIM / 64, NDESC, 4), 512, 0, stream>>>(Hb, wd, offs, desc, perm, wsel, y);
}

// Round 16
// 160.072 us; speedup vs baseline: 1.8919x; 1.3768x over previous
//
#include <hip/hip_runtime.h>
#include <hip/hip_bf16.h>

typedef __attribute__((ext_vector_type(8))) short bf16x8;
typedef __attribute__((ext_vector_type(4))) float f32x4;
typedef unsigned short u16;

#define NTOK 2048
#define DDIM 1024
#define HDIM 4096
#define KEXP 8

#define BM 320   // covers any realistic expert count in ONE tile (counts ~256±15)
#define BK 64
#define NDESC 16

__device__ __forceinline__ u16 f2bf(float f) {
  __hip_bfloat16 b = __float2bfloat16(f);   // RNE; pairs fuse to v_cvt_pk_bf16_f32
  union { __hip_bfloat16 b; u16 u; } c; c.b = b; return c.u;
}
__device__ __forceinline__ unsigned pk2(float a, float b) {
  return (unsigned)f2bf(a) | ((unsigned)f2bf(b) << 16);
}
__device__ __forceinline__ float bf2f(unsigned hi16) {  // hi16 already in [31:16]
  union { unsigned u; float f; } c; c.u = hi16; return c.f;
}

// fenced raw barrier: own DS ops drained, no vmcnt drain, no code motion across
#define BAR() do { \
  asm volatile("s_waitcnt lgkmcnt(0)" ::: "memory"); \
  __builtin_amdgcn_sched_barrier(0); \
  __builtin_amdgcn_s_barrier(); \
  __builtin_amdgcn_sched_barrier(0); \
} while (0)

// ---------------- routing: counting sort + tile worklist ----------------
__global__ void route_kernel(const float* __restrict__ cw, int* __restrict__ offs,
                             int* __restrict__ perm, float* __restrict__ wsel,
                             int* __restrict__ desc) {
  __shared__ int cnt[KEXP];
  __shared__ int base[KEXP];
  const int t = threadIdx.x;  // 256 threads, 8 tokens each
  if (t < KEXP) cnt[t] = 0;
  __syncthreads();
  int eid[8]; float wv[8];
  #pragma unroll
  for (int i = 0; i < 8; i++) {
    const int tok = t * 8 + i;
    const float* p = cw + tok * KEXP;
    int best = 0; float bw = p[0];
    #pragma unroll
    for (int k = 1; k < KEXP; k++) { float v = p[k]; if (v > bw) { bw = v; best = k; } }
    eid[i] = best; wv[i] = bw;
    atomicAdd(&cnt[best], 1);
  }
  __syncthreads();
  if (t == 0) {
    int s = 0, nd = 0;
    for (int k = 0; k < KEXP; k++) {
      const int ck = cnt[k];
      base[k] = s; offs[k] = s;
      for (int m0 = 0; m0 < ck && nd < NDESC; m0 += BM)
        desc[nd++] = (k << 12) | (s + m0);   // pack expert(3b) | slot0(12b)
      s += ck;
    }
    offs[KEXP] = s;
    for (; nd < NDESC; nd++) desc[nd] = -1;
  }
  __syncthreads();
  #pragma unroll
  for (int i = 0; i < 8; i++) {
    const int tok = t * 8 + i;
    const int pos = atomicAdd(&base[eid[i]], 1);
    perm[pos] = tok;
    wsel[pos] = wv[i];
  }
}

// ---------------- gather x rows into expert-sorted bf16 ----------------
__global__ void gather_x(const float* __restrict__ x, const int* __restrict__ perm,
                         u16* __restrict__ Xb) {
  const int slot = blockIdx.x;
  const int tok = perm[slot];
  const int t = threadIdx.x;  // 256
  float4 v = ((const float4*)(x + (size_t)tok * DDIM))[t];
  ushort4 o; o.x = f2bf(v.x); o.y = f2bf(v.y); o.z = f2bf(v.z); o.w = f2bf(v.w);
  ((ushort4*)(Xb + (size_t)slot * DDIM))[t] = o;
}

// ---------------- pass A: {G,U} = X @ {wg,wu}  (blockIdx.z selects matrix) ----------------
// EXACT clone of the proven-fast pass-2 template: 1024 thr = 16 waves (4m x 4n),
// BM=320, BN=128, BK=64, wave tile 80x32, acc=40. Compute-first phases, A-dbuf
// (issue-early/write-late), swizzled B dbuf, raw fenced barrier, no vmcnt(0).
__global__ __launch_bounds__(1024, 4) void gemm_nt(
    const u16* __restrict__ Xb,
    const float* __restrict__ wg, const float* __restrict__ wu,
    const int* __restrict__ offs, const int* __restrict__ desc,
    u16* __restrict__ Gb, u16* __restrict__ Ub) {
  __shared__ u16 As[2][BM * 64];       // 80 KB
  __shared__ u16 Bs[2][128 * 64];      // 32 KB

  const int d = desc[blockIdx.y];
  if (d < 0) return;
  const int e = d >> 12;
  const int slot0 = d & 0xFFF;
  const int Msub = offs[e + 1] - slot0;
  const int n0 = blockIdx.x * 128;
  const int mat = blockIdx.z;

  const float* Wsrc = (mat ? wu : wg) + (size_t)e * DDIM * HDIM;
  u16* Out = mat ? Ub : Gb;

  const int t = threadIdx.x;
  const int lane = t & 63;
  const int W = t >> 6;
  const int wm = W >> 2;   // 4 m-strips of 80
  const int wn = W & 3;    // 4 n-strips of 32
  const int l15 = lane & 15;
  const int lhi = lane >> 4;

  const bool do_a = t < 640;
  const int a_row = t >> 1;
  const int a_c0 = (t & 1) * 4;
  const u16* a_src = Xb + (size_t)min(slot0 + a_row, NTOK - 1) * DDIM + a_c0 * 8;
  const int a_swz = a_row & 7;

  // B staging: thread -> (n = t&127, k-chunk c = t>>7); k-row stride = HDIM
  const int b_n = t & 127;
  const int b_c = t >> 7;
  const float* b_src = Wsrc + (size_t)(b_c * 8) * HDIM + n0 + b_n;
  const int b_off = b_n * 64 + ((b_c ^ (b_n & 7)) << 3);

  float bR[8];
  uint4 aT0, aT1, aT2, aT3;
  f32x4 acc[5][2] = {};

  #define AISSUE(tile) if (do_a) { const uint4* p_ = (const uint4*)(a_src + (tile) * BK); \
    aT0 = p_[0]; aT1 = p_[1]; aT2 = p_[2]; aT3 = p_[3]; }
  #define AWRITE(buf) if (do_a) { u16* base_ = &As[buf][a_row * 64]; \
    *(uint4*)(base_ + (((a_c0 + 0) ^ a_swz) << 3)) = aT0; \
    *(uint4*)(base_ + (((a_c0 + 1) ^ a_swz) << 3)) = aT1; \
    *(uint4*)(base_ + (((a_c0 + 2) ^ a_swz) << 3)) = aT2; \
    *(uint4*)(base_ + (((a_c0 + 3) ^ a_swz) << 3)) = aT3; }
  #define LOADB(tile) { const float* p_ = b_src + (size_t)(tile) * BK * HDIM; \
    _Pragma("unroll") for (int j = 0; j < 8; j++) bR[j] = p_[(size_t)j * HDIM]; }
  #define WRITEB(buf) { uint4 w_; \
    w_.x = pk2(bR[0], bR[1]); w_.y = pk2(bR[2], bR[3]); \
    w_.z = pk2(bR[4], bR[5]); w_.w = pk2(bR[6], bR[7]); \
    *(uint4*)(&Bs[buf][b_off]) = w_; }
  #define COMPUTE(buf) { _Pragma("unroll") for (int ks = 0; ks < 2; ks++) { \
      const int cx_ = (((ks << 2) + lhi) ^ (l15 & 7)) << 3; \
      bf16x8 bf0_ = *(const bf16x8*)(&Bs[buf][(wn * 32 + l15) * 64] + cx_); \
      bf16x8 bf1_ = *(const bf16x8*)(&Bs[buf][(wn * 32 + 16 + l15) * 64] + cx_); \
      _Pragma("unroll") for (int fm = 0; fm < 5; fm++) { \
        bf16x8 af_ = *(const bf16x8*)(&As[buf][(wm * 80 + fm * 16 + l15) * 64] + cx_); \
        acc[fm][0] = __builtin_amdgcn_mfma_f32_16x16x32_bf16(af_, bf0_, acc[fm][0], 0, 0, 0); \
        acc[fm][1] = __builtin_amdgcn_mfma_f32_16x16x32_bf16(af_, bf1_, acc[fm][1], 0, 0, 0); } } }

  LOADB(0);
  AISSUE(0);
  WRITEB(0);
  LOADB(1);
  AWRITE(0);
  BAR();

  #pragma unroll 1
  for (int it = 0; it < 16; it += 2) {
    if (it + 1 < 16) AISSUE(it + 1);
    __builtin_amdgcn_sched_barrier(0);
    COMPUTE(0);
    if (it + 1 < 16) {
      WRITEB(1);
      if (it + 2 < 16) LOADB(it + 2);
      AWRITE(1);
    }
    BAR();
    if (it + 2 < 16) AISSUE(it + 2);
    __builtin_amdgcn_sched_barrier(0);
    COMPUTE(1);
    if (it + 2 < 16) {
      WRITEB(0);
      if (it + 3 < 16) LOADB(it + 3);
      AWRITE(0);
    }
    BAR();
  }
  #undef AISSUE
  #undef AWRITE
  #undef LOADB
  #undef WRITEB
  #undef COMPUTE

  // epilogue: raw matmul -> bf16 (C/D map: col=lane&15, row=(lane>>4)*4+i)
  #pragma unroll
  for (int fm = 0; fm < 5; fm++) {
    #pragma unroll
    for (int i = 0; i < 4; i++) {
      const int row = wm * 80 + fm * 16 + lhi * 4 + i;
      if (row < Msub) {
        const size_t base = (size_t)(slot0 + row) * HDIM + n0 + wn * 32;
        Out[base + l15] = f2bf(acc[fm][0][i]);
        Out[base + 16 + l15] = f2bf(acc[fm][1][i]);
      }
    }
  }
}

// ---------------- combine: Hb(=Gb in-place) = silu(G) * U ----------------
__global__ void swiglu_combine(u16* __restrict__ Gb, const u16* __restrict__ Ub) {
  const size_t i = ((size_t)blockIdx.x * 256 + threadIdx.x) * 8;
  uint4 gv = *(const uint4*)(Gb + i);
  uint4 uv = *(const uint4*)(Ub + i);
  const unsigned* gp = (const unsigned*)&gv;
  const unsigned* up = (const unsigned*)&uv;
  uint4 ov;
  unsigned* op = (unsigned*)&ov;
  #pragma unroll
  for (int j = 0; j < 4; j++) {
    const float g0 = bf2f(gp[j] << 16), g1 = bf2f(gp[j] & 0xFFFF0000u);
    const float u0 = bf2f(up[j] << 16), u1 = bf2f(up[j] & 0xFFFF0000u);
    const float h0 = (g0 / (1.0f + __expf(-g0))) * u0;
    const float h1 = (g1 / (1.0f + __expf(-g1))) * u1;
    op[j] = pk2(h0, h1);
  }
  *(uint4*)(Gb + i) = ov;
}

// ---------------- pass 2: Y = (H @ wd) * wsel, split-K=4, scatter-add ----------------
// R13-verbatim (measured ~3.8 TB/s). BN=128, wave tile 80x32, 256 useful blocks.
__global__ __launch_bounds__(1024, 4) void gemm_down(
    const u16* __restrict__ Hb, const float* __restrict__ wd,
    const int* __restrict__ offs, const int* __restrict__ desc,
    const int* __restrict__ perm, const float* __restrict__ wsel,
    float* __restrict__ y) {
  __shared__ u16 As[2][BM * 64];       // 80 KB
  __shared__ u16 Bs[2][128 * 64];      // 32 KB

  const int d = desc[blockIdx.y];
  if (d < 0) return;
  const int e = d >> 12;
  const int slot0 = d & 0xFFF;
  const int Msub = offs[e + 1] - slot0;
  const int n0 = blockIdx.x * 128;
  const int kbase = blockIdx.z * (HDIM / 4);

  const float* Wd = wd + (size_t)e * HDIM * DDIM;

  const int t = threadIdx.x;
  const int lane = t & 63;
  const int W = t >> 6;
  const int wm = W >> 2;   // 4 m-strips of 80
  const int wn = W & 3;    // 4 n-strips of 32
  const int l15 = lane & 15;
  const int lhi = lane >> 4;

  const bool do_a = t < 640;
  const int a_row = t >> 1;
  const int a_c0 = (t & 1) * 4;
  const u16* a_src = Hb + (size_t)min(slot0 + a_row, NTOK - 1) * HDIM + kbase + a_c0 * 8;
  const int a_swz = a_row & 7;

  const int b_n = t & 127;
  const int b_c = t >> 7;
  const float* b_src = Wd + (size_t)(kbase + b_c * 8) * DDIM + n0 + b_n;
  const int b_off = b_n * 64 + ((b_c ^ (b_n & 7)) << 3);

  float bR[8];
  uint4 aT0, aT1, aT2, aT3;
  f32x4 acc[5][2] = {};

  #define AISSUE(tile) if (do_a) { const uint4* p_ = (const uint4*)(a_src + (tile) * BK); \
    aT0 = p_[0]; aT1 = p_[1]; aT2 = p_[2]; aT3 = p_[3]; }
  #define AWRITE(buf) if (do_a) { u16* base_ = &As[buf][a_row * 64]; \
    *(uint4*)(base_ + (((a_c0 + 0) ^ a_swz) << 3)) = aT0; \
    *(uint4*)(base_ + (((a_c0 + 1) ^ a_swz) << 3)) = aT1; \
    *(uint4*)(base_ + (((a_c0 + 2) ^ a_swz) << 3)) = aT2; \
    *(uint4*)(base_ + (((a_c0 + 3) ^ a_swz) << 3)) = aT3; }
  #define LOADB(tile) { const float* p_ = b_src + (size_t)(tile) * BK * DDIM; \
    _Pragma("unroll") for (int j = 0; j < 8; j++) bR[j] = p_[(size_t)j * DDIM]; }
  #define WRITEB(buf) { uint4 w_; \
    w_.x = pk2(bR[0], bR[1]); w_.y = pk2(bR[2], bR[3]); \
    w_.z = pk2(bR[4], bR[5]); w_.w = pk2(bR[6], bR[7]); \
    *(uint4*)(&Bs[buf][b_off]) = w_; }
  #define COMPUTE(buf) { _Pragma("unroll") for (int ks = 0; ks < 2; ks++) { \
      const int cx_ = (((ks << 2) + lhi) ^ (l15 & 7)) << 3; \
      bf16x8 bf0_ = *(const bf16x8*)(&Bs[buf][(wn * 32 + l15) * 64] + cx_); \
      bf16x8 bf1_ = *(const bf16x8*)(&Bs[buf][(wn * 32 + 16 + l15) * 64] + cx_); \
      _Pragma("unroll") for (int fm = 0; fm < 5; fm++) { \
        bf16x8 af_ = *(const bf16x8*)(&As[buf][(wm * 80 + fm * 16 + l15) * 64] + cx_); \
        acc[fm][0] = __builtin_amdgcn_mfma_f32_16x16x32_bf16(af_, bf0_, acc[fm][0], 0, 0, 0); \
        acc[fm][1] = __builtin_amdgcn_mfma_f32_16x16x32_bf16(af_, bf1_, acc[fm][1], 0, 0, 0); } } }

  LOADB(0);
  AISSUE(0);
  WRITEB(0);
  LOADB(1);
  AWRITE(0);
  BAR();

  #pragma unroll 1
  for (int it = 0; it < 16; it += 2) {
    if (it + 1 < 16) AISSUE(it + 1);
    __builtin_amdgcn_sched_barrier(0);
    COMPUTE(0);
    if (it + 1 < 16) {
      WRITEB(1);
      if (it + 2 < 16) LOADB(it + 2);
      AWRITE(1);
    }
    BAR();
    if (it + 2 < 16) AISSUE(it + 2);
    __builtin_amdgcn_sched_barrier(0);
    COMPUTE(1);
    if (it + 2 < 16) {
      WRITEB(0);
      if (it + 3 < 16) LOADB(it + 3);
      AWRITE(0);
    }
    BAR();
  }
  #undef AISSUE
  #undef AWRITE
  #undef LOADB
  #undef WRITEB
  #undef COMPUTE

  // epilogue: scale by routing weight, scatter-add (4 K-quarters, commutative)
  #pragma unroll
  for (int fm = 0; fm < 5; fm++) {
    #pragma unroll
    for (int i = 0; i < 4; i++) {
      const int row = wm * 80 + fm * 16 + lhi * 4 + i;
      if (row < Msub) {
        const int slot = slot0 + row;
        const int tok = perm[slot];
        const float w = wsel[slot];
        const size_t base = (size_t)tok * DDIM + n0 + wn * 32;
        atomicAdd(y + base + l15, acc[fm][0][i] * w);
        atomicAdd(y + base + 16 + l15, acc[fm][1][i] * w);
      }
    }
  }
}

extern "C" void kernel_launch(void* const* d_in, const int* in_sizes, int n_in,
                              void* d_out, int out_size, void* d_ws, size_t ws_size,
                              hipStream_t stream) {
  const float* x  = (const float*)d_in[0];
  const float* cw = (const float*)d_in[1];
  const float* wg = (const float*)d_in[2];
  const float* wu = (const float*)d_in[3];
  const float* wd = (const float*)d_in[4];
  float* y = (float*)d_out;

  char* ws = (char*)d_ws;
  int* offs   = (int*)ws;                          // 16 ints
  int* desc   = (int*)(ws + 64);                   // 16 ints
  int* perm   = (int*)(ws + 128);                  // 2048 ints
  float* wsel = (float*)(ws + 128 + NTOK * 4);     // 2048 floats
  u16* Xb = (u16*)(ws + 32768);                                        // 4 MB
  u16* Gb = (u16*)(ws + 32768 + (size_t)NTOK * DDIM * 2);              // 16 MB (becomes Hb)
  u16* Ub = (u16*)(ws + 32768 + (size_t)NTOK * DDIM * 2
                          + (size_t)NTOK * HDIM * 2);                  // 16 MB

  hipMemsetAsync(d_out, 0, (size_t)NTOK * DDIM * sizeof(float), stream);
  route_kernel<<<1, 256, 0, stream>>>(cw, offs, perm, wsel, desc);
  gather_x<<<NTOK, 256, 0, stream>>>(x, perm, Xb);
  gemm_nt<<<dim3(HDIM / 128, NDESC, 2), 1024, 0, stream>>>(Xb, wg, wu, offs, desc, Gb, Ub);
  swiglu_combine<<<(NTOK * HDIM / 8) / 256, 256, 0, stream>>>(Gb, Ub);
  gemm_down<<<dim3(DDIM / 128, NDESC, 4), 1024, 0, stream>>>(Gb, wd, offs, desc, perm, wsel, y);
}

// Round 17
// 158.081 us; speedup vs baseline: 1.9157x; 1.0126x over previous
//
#include <hip/hip_runtime.h>
#include <hip/hip_bf16.h>

typedef __attribute__((ext_vector_type(8))) short bf16x8;
typedef __attribute__((ext_vector_type(4))) float f32x4;
typedef unsigned short u16;

#define NTOK 2048
#define DDIM 1024
#define HDIM 4096
#define KEXP 8

#define BM 320   // covers any realistic expert count in ONE tile (counts ~256±15)
#define BK 64
#define NDESC 16

__device__ __forceinline__ u16 f2bf(float f) {
  __hip_bfloat16 b = __float2bfloat16(f);   // RNE; pairs fuse to v_cvt_pk_bf16_f32
  union { __hip_bfloat16 b; u16 u; } c; c.b = b; return c.u;
}
__device__ __forceinline__ unsigned pk2(float a, float b) {
  return (unsigned)f2bf(a) | ((unsigned)f2bf(b) << 16);
}

// fenced raw barrier: own DS ops drained, no vmcnt drain, no code motion across
#define BAR() do { \
  asm volatile("s_waitcnt lgkmcnt(0)" ::: "memory"); \
  __builtin_amdgcn_sched_barrier(0); \
  __builtin_amdgcn_s_barrier(); \
  __builtin_amdgcn_sched_barrier(0); \
} while (0)

// ---------------- routing: counting sort + tile worklist ----------------
__global__ void route_kernel(const float* __restrict__ cw, int* __restrict__ offs,
                             int* __restrict__ perm, float* __restrict__ wsel,
                             int* __restrict__ desc) {
  __shared__ int cnt[KEXP];
  __shared__ int base[KEXP];
  const int t = threadIdx.x;  // 256 threads, 8 tokens each
  if (t < KEXP) cnt[t] = 0;
  __syncthreads();
  int eid[8]; float wv[8];
  #pragma unroll
  for (int i = 0; i < 8; i++) {
    const int tok = t * 8 + i;
    const float* p = cw + tok * KEXP;
    int best = 0; float bw = p[0];
    #pragma unroll
    for (int k = 1; k < KEXP; k++) { float v = p[k]; if (v > bw) { bw = v; best = k; } }
    eid[i] = best; wv[i] = bw;
    atomicAdd(&cnt[best], 1);
  }
  __syncthreads();
  if (t == 0) {
    int s = 0, nd = 0;
    for (int k = 0; k < KEXP; k++) {
      const int ck = cnt[k];
      base[k] = s; offs[k] = s;
      for (int m0 = 0; m0 < ck && nd < NDESC; m0 += BM)
        desc[nd++] = (k << 12) | (s + m0);   // pack expert(3b) | slot0(12b)
      s += ck;
    }
    offs[KEXP] = s;
    for (; nd < NDESC; nd++) desc[nd] = -1;
  }
  __syncthreads();
  #pragma unroll
  for (int i = 0; i < 8; i++) {
    const int tok = t * 8 + i;
    const int pos = atomicAdd(&base[eid[i]], 1);
    perm[pos] = tok;
    wsel[pos] = wv[i];
  }
}

// ---------------- gather x rows into expert-sorted bf16 ----------------
__global__ void gather_x(const float* __restrict__ x, const int* __restrict__ perm,
                         u16* __restrict__ Xb) {
  const int slot = blockIdx.x;
  const int tok = perm[slot];
  const int t = threadIdx.x;  // 256
  float4 v = ((const float4*)(x + (size_t)tok * DDIM))[t];
  ushort4 o; o.x = f2bf(v.x); o.y = f2bf(v.y); o.z = f2bf(v.z); o.w = f2bf(v.w);
  ((ushort4*)(Xb + (size_t)slot * DDIM))[t] = o;
}

// ---------------- pass 1: H = silu(X@wg) * (X@wu) ----------------
// R13 base (best measured) + B DEPTH-2 prefetch: two bR sets ping-pong so each
// B tile has TWO full phases between issue and LDS-write consumption --
// tolerates the 16KB-row-stride channel-aliased HBM service tails.
// 1024 thr = 16 waves (4m x 4n), BM=320, BN=64, BK=64. Swizzled LDS, dbuf,
// compute-first phases, raw fenced barrier, no vmcnt(0) in loop.
__global__ __launch_bounds__(1024, 4) void gemm_swiglu(
    const u16* __restrict__ Xb,
    const float* __restrict__ wg, const float* __restrict__ wu,
    const int* __restrict__ offs, const int* __restrict__ desc,
    u16* __restrict__ Hb) {
  __shared__ u16 As[2][BM * 64];       // 80 KB
  __shared__ u16 Bs[2][2][64 * 64];    // 32 KB  [buf][mat][n*64 ^swz]

  const int d = desc[blockIdx.y];
  if (d < 0) return;
  const int e = d >> 12;
  const int slot0 = d & 0xFFF;
  const int Msub = offs[e + 1] - slot0;
  const int n0 = blockIdx.x * 64;

  const int t = threadIdx.x;
  const int lane = t & 63;
  const int W = t >> 6;
  const int wm = W >> 2;     // 4 m-strips of 80 rows
  const int wn = W & 3;      // 4 n-strips of 16 cols
  const int l15 = lane & 15;
  const int lhi = lane >> 4;

  // A staging: threads 0..639 -> row t>>1, chunks (t&1)*4 .. +3 (32 elems)
  const bool do_a = t < 640;
  const int a_row = t >> 1;
  const int a_c0 = (t & 1) * 4;
  const u16* a_src = Xb + (size_t)min(slot0 + a_row, NTOK - 1) * DDIM + a_c0 * 8;
  const int a_swz = a_row & 7;

  // B staging: t<512 -> G(wg), else U(wu); thread -> (n = tb&63, chunk c = tb>>6)
  const int tb = t & 511;
  const int matsel = t >> 9;
  const float* b_base = (matsel ? wu : wg) + (size_t)e * DDIM * HDIM;
  const int b_n = tb & 63;
  const int b_c = tb >> 6;
  const float* b_src = b_base + (size_t)(b_c * 8) * HDIM + n0 + b_n;
  const int b_off = b_n * 64 + ((b_c ^ (b_n & 7)) << 3);

  float bA[8], bB[8];                  // depth-2 B prefetch sets
  uint4 aT0, aT1, aT2, aT3;            // A in-flight regs (live across COMPUTE)
  f32x4 accg[5] = {};
  f32x4 accu[5] = {};

  #define AISSUE(tile) if (do_a) { const uint4* p_ = (const uint4*)(a_src + (tile) * BK); \
    aT0 = p_[0]; aT1 = p_[1]; aT2 = p_[2]; aT3 = p_[3]; }
  #define AWRITE(buf) if (do_a) { u16* base_ = &As[buf][a_row * 64]; \
    *(uint4*)(base_ + (((a_c0 + 0) ^ a_swz) << 3)) = aT0; \
    *(uint4*)(base_ + (((a_c0 + 1) ^ a_swz) << 3)) = aT1; \
    *(uint4*)(base_ + (((a_c0 + 2) ^ a_swz) << 3)) = aT2; \
    *(uint4*)(base_ + (((a_c0 + 3) ^ a_swz) << 3)) = aT3; }
  #define LOADB(set, tile) { const float* p_ = b_src + (size_t)(tile) * BK * HDIM; \
    _Pragma("unroll") for (int j = 0; j < 8; j++) set[j] = p_[(size_t)j * HDIM]; }
  #define WRITEB(set, buf) { uint4 w_; \
    w_.x = pk2(set[0], set[1]); w_.y = pk2(set[2], set[3]); \
    w_.z = pk2(set[4], set[5]); w_.w = pk2(set[6], set[7]); \
    *(uint4*)(&Bs[buf][matsel][b_off]) = w_; }
  #define COMPUTE(buf) { _Pragma("unroll") for (int ks = 0; ks < 2; ks++) { \
      const int cx_ = (((ks << 2) + lhi) ^ (l15 & 7)) << 3; \
      bf16x8 bg_ = *(const bf16x8*)(&Bs[buf][0][(wn * 16 + l15) * 64] + cx_); \
      bf16x8 bu_ = *(const bf16x8*)(&Bs[buf][1][(wn * 16 + l15) * 64] + cx_); \
      _Pragma("unroll") for (int fm = 0; fm < 5; fm++) { \
        bf16x8 af_ = *(const bf16x8*)(&As[buf][(wm * 80 + fm * 16 + l15) * 64] + cx_); \
        accg[fm] = __builtin_amdgcn_mfma_f32_16x16x32_bf16(af_, bg_, accg[fm], 0, 0, 0); \
        accu[fm] = __builtin_amdgcn_mfma_f32_16x16x32_bf16(af_, bu_, accu[fm], 0, 0, 0); } } }

  // prologue: tile0 -> buf0 (via bA transiently); then bA=tile1, bB=tile2
  LOADB(bA, 0);
  AISSUE(0);
  WRITEB(bA, 0);
  LOADB(bA, 1);
  LOADB(bB, 2);
  AWRITE(0);
  BAR();

  #pragma unroll 1
  for (int it = 0; it < 16; it += 2) {
    // even phase: compute tile it (buf0); stage tile it+1 (bA) -> buf1; refill bA=it+3
    if (it + 1 < 16) AISSUE(it + 1);
    __builtin_amdgcn_sched_barrier(0);
    COMPUTE(0);
    if (it + 1 < 16) {
      WRITEB(bA, 1);
      if (it + 3 < 16) LOADB(bA, it + 3);
      AWRITE(1);
    }
    BAR();
    // odd phase: compute tile it+1 (buf1); stage tile it+2 (bB) -> buf0; refill bB=it+4
    if (it + 2 < 16) AISSUE(it + 2);
    __builtin_amdgcn_sched_barrier(0);
    COMPUTE(1);
    if (it + 2 < 16) {
      WRITEB(bB, 0);
      if (it + 4 < 16) LOADB(bB, it + 4);
      AWRITE(0);
    }
    BAR();
  }
  #undef AISSUE
  #undef AWRITE
  #undef LOADB
  #undef WRITEB
  #undef COMPUTE

  // epilogue: silu(g)*u -> bf16 Hb  (C/D map: col=lane&15, row=(lane>>4)*4+i)
  #pragma unroll
  for (int fm = 0; fm < 5; fm++) {
    #pragma unroll
    for (int i = 0; i < 4; i++) {
      const int row = wm * 80 + fm * 16 + lhi * 4 + i;
      if (row < Msub) {
        const float g = accg[fm][i];
        const float u = accu[fm][i];
        const float h = (g / (1.0f + __expf(-g))) * u;
        Hb[(size_t)(slot0 + row) * HDIM + n0 + wn * 16 + l15] = f2bf(h);
      }
    }
  }
}

// ---------------- pass 2: Y = (H @ wd) * wsel, split-K=4, scatter-add ----------------
// R13 base + B depth-2. BN=128, wave tile 80x32, 256 useful blocks = 1/CU.
__global__ __launch_bounds__(1024, 4) void gemm_down(
    const u16* __restrict__ Hb, const float* __restrict__ wd,
    const int* __restrict__ offs, const int* __restrict__ desc,
    const int* __restrict__ perm, const float* __restrict__ wsel,
    float* __restrict__ y) {
  __shared__ u16 As[2][BM * 64];       // 80 KB
  __shared__ u16 Bs[2][128 * 64];      // 32 KB

  const int d = desc[blockIdx.y];
  if (d < 0) return;
  const int e = d >> 12;
  const int slot0 = d & 0xFFF;
  const int Msub = offs[e + 1] - slot0;
  const int n0 = blockIdx.x * 128;
  const int kbase = blockIdx.z * (HDIM / 4);

  const float* Wd = wd + (size_t)e * HDIM * DDIM;

  const int t = threadIdx.x;
  const int lane = t & 63;
  const int W = t >> 6;
  const int wm = W >> 2;   // 4 m-strips of 80
  const int wn = W & 3;    // 4 n-strips of 32
  const int l15 = lane & 15;
  const int lhi = lane >> 4;

  const bool do_a = t < 640;
  const int a_row = t >> 1;
  const int a_c0 = (t & 1) * 4;
  const u16* a_src = Hb + (size_t)min(slot0 + a_row, NTOK - 1) * HDIM + kbase + a_c0 * 8;
  const int a_swz = a_row & 7;

  const int b_n = t & 127;
  const int b_c = t >> 7;
  const float* b_src = Wd + (size_t)(kbase + b_c * 8) * DDIM + n0 + b_n;
  const int b_off = b_n * 64 + ((b_c ^ (b_n & 7)) << 3);

  float bA[8], bB[8];
  uint4 aT0, aT1, aT2, aT3;
  f32x4 acc[5][2] = {};

  #define AISSUE(tile) if (do_a) { const uint4* p_ = (const uint4*)(a_src + (tile) * BK); \
    aT0 = p_[0]; aT1 = p_[1]; aT2 = p_[2]; aT3 = p_[3]; }
  #define AWRITE(buf) if (do_a) { u16* base_ = &As[buf][a_row * 64]; \
    *(uint4*)(base_ + (((a_c0 + 0) ^ a_swz) << 3)) = aT0; \
    *(uint4*)(base_ + (((a_c0 + 1) ^ a_swz) << 3)) = aT1; \
    *(uint4*)(base_ + (((a_c0 + 2) ^ a_swz) << 3)) = aT2; \
    *(uint4*)(base_ + (((a_c0 + 3) ^ a_swz) << 3)) = aT3; }
  #define LOADB(set, tile) { const float* p_ = b_src + (size_t)(tile) * BK * DDIM; \
    _Pragma("unroll") for (int j = 0; j < 8; j++) set[j] = p_[(size_t)j * DDIM]; }
  #define WRITEB(set, buf) { uint4 w_; \
    w_.x = pk2(set[0], set[1]); w_.y = pk2(set[2], set[3]); \
    w_.z = pk2(set[4], set[5]); w_.w = pk2(set[6], set[7]); \
    *(uint4*)(&Bs[buf][b_off]) = w_; }
  #define COMPUTE(buf) { _Pragma("unroll") for (int ks = 0; ks < 2; ks++) { \
      const int cx_ = (((ks << 2) + lhi) ^ (l15 & 7)) << 3; \
      bf16x8 bf0_ = *(const bf16x8*)(&Bs[buf][(wn * 32 + l15) * 64] + cx_); \
      bf16x8 bf1_ = *(const bf16x8*)(&Bs[buf][(wn * 32 + 16 + l15) * 64] + cx_); \
      _Pragma("unroll") for (int fm = 0; fm < 5; fm++) { \
        bf16x8 af_ = *(const bf16x8*)(&As[buf][(wm * 80 + fm * 16 + l15) * 64] + cx_); \
        acc[fm][0] = __builtin_amdgcn_mfma_f32_16x16x32_bf16(af_, bf0_, acc[fm][0], 0, 0, 0); \
        acc[fm][1] = __builtin_amdgcn_mfma_f32_16x16x32_bf16(af_, bf1_, acc[fm][1], 0, 0, 0); } } }

  LOADB(bA, 0);
  AISSUE(0);
  WRITEB(bA, 0);
  LOADB(bA, 1);
  LOADB(bB, 2);
  AWRITE(0);
  BAR();

  #pragma unroll 1
  for (int it = 0; it < 16; it += 2) {
    if (it + 1 < 16) AISSUE(it + 1);
    __builtin_amdgcn_sched_barrier(0);
    COMPUTE(0);
    if (it + 1 < 16) {
      WRITEB(bA, 1);
      if (it + 3 < 16) LOADB(bA, it + 3);
      AWRITE(1);
    }
    BAR();
    if (it + 2 < 16) AISSUE(it + 2);
    __builtin_amdgcn_sched_barrier(0);
    COMPUTE(1);
    if (it + 2 < 16) {
      WRITEB(bB, 0);
      if (it + 4 < 16) LOADB(bB, it + 4);
      AWRITE(0);
    }
    BAR();
  }
  #undef AISSUE
  #undef AWRITE
  #undef LOADB
  #undef WRITEB
  #undef COMPUTE

  // epilogue: scale by routing weight, scatter-add (4 K-quarters, commutative)
  #pragma unroll
  for (int fm = 0; fm < 5; fm++) {
    #pragma unroll
    for (int i = 0; i < 4; i++) {
      const int row = wm * 80 + fm * 16 + lhi * 4 + i;
      if (row < Msub) {
        const int slot = slot0 + row;
        const int tok = perm[slot];
        const float w = wsel[slot];
        const size_t base = (size_t)tok * DDIM + n0 + wn * 32;
        atomicAdd(y + base + l15, acc[fm][0][i] * w);
        atomicAdd(y + base + 16 + l15, acc[fm][1][i] * w);
      }
    }
  }
}

extern "C" void kernel_launch(void* const* d_in, const int* in_sizes, int n_in,
                              void* d_out, int out_size, void* d_ws, size_t ws_size,
                              hipStream_t stream) {
  const float* x  = (const float*)d_in[0];
  const float* cw = (const float*)d_in[1];
  const float* wg = (const float*)d_in[2];
  const float* wu = (const float*)d_in[3];
  const float* wd = (const float*)d_in[4];
  float* y = (float*)d_out;

  char* ws = (char*)d_ws;
  int* offs   = (int*)ws;                          // 16 ints
  int* desc   = (int*)(ws + 64);                   // 16 ints
  int* perm   = (int*)(ws + 128);                  // 2048 ints
  float* wsel = (float*)(ws + 128 + NTOK * 4);     // 2048 floats
  u16* Xb = (u16*)(ws + 32768);                                    // 4 MB
  u16* Hb = (u16*)(ws + 32768 + (size_t)NTOK * DDIM * 2);          // 16 MB

  hipMemsetAsync(d_out, 0, (size_t)NTOK * DDIM * sizeof(float), stream);
  route_kernel<<<1, 256, 0, stream>>>(cw, offs, perm, wsel, desc);
  gather_x<<<NTOK, 256, 0, stream>>>(x, perm, Xb);
  gemm_swiglu<<<dim3(HDIM / 64, NDESC), 1024, 0, stream>>>(Xb, wg, wu, offs, desc, Hb);
  gemm_down<<<dim3(DDIM / 128, NDESC, 4), 1024, 0, stream>>>(Hb, wd, offs, desc, perm, wsel, y);
}